// Round 8
// baseline (16108.653 us; speedup 1.0000x reference)
//
#include <hip/hip_runtime.h>

typedef unsigned int u32;
typedef unsigned short u16;
typedef unsigned long long u64;

#define T_STEPS 2048
#define BATCH   32
#define HID     512
#define INDIM   128
#define OUTD    128
#define NG      2048
#define L0_WGS  64
#define L1_WGS  64
#define FC_WGS  4
#define NWG     (L0_WGS + L1_WGS + FC_WGS)
#define BH      (BATCH * HID)
#define SLOT_Q  4096              // u64 units per 32 KB h slot
#define HQS     130               // padded LDS row stride (u64) — bank spread

#define HID_OFF 8388608           // 32*2048*128
#define CN_OFF  8396800           // + 2*32*128

// ws layout (bytes) — v5 layout preserved; deep-history rings appended
#define WS_FLAGS   0                         // flags + counters (16 KB reserved)
#define WS_H0RING  16384
#define WS_H1RING  (WS_H0RING + 131072)      // 4*32*512*2
#define WS_BIAS0   (WS_H1RING + 131072)
#define WS_BIAS1   (WS_BIAS0 + 8192)
#define WS_WFC     (WS_BIAS1 + 8192)         // 4 * 16384 u16
#define WS_WL0     (WS_WFC + 131072)         // 64 * 20480 u16
#define WS_WL1     (WS_WL0 + 2621440)        // 64 * 32768 u16
#define WS_XBF     (WS_WL1 + 4194304)        // 32*2048*128 u16 = 16 MB
#define WS_H0DEEP  (WS_XBF + 16777216)       // 2049 slots x 32 KB (slot 0 = h[-1] = 0)
#define WS_H1DEEP  (WS_H0DEEP + 67141632)    // 2049 slots x 32 KB
#define WS_DEEPEND (WS_H1DEEP + 67141632)    // 158,302,208 B required for deep mode

// aggregated epoch counters (deep mode), u32 @ 64B stride, inside flag region
#define F_CNT0  3584              // u32 index: byte 14336; [8] slots
#define F_CNT1  3712              // byte 14848; [8] slots

typedef __bf16 bf16x8 __attribute__((ext_vector_type(8)));
typedef float  f32x4  __attribute__((ext_vector_type(4)));
typedef unsigned int u32x4 __attribute__((ext_vector_type(4)));

__device__ __forceinline__ u16 f2bf(float f) {
    u32 u = __float_as_uint(f);
    u32 r = u + 0x7FFFu + ((u >> 16) & 1u);
    return (u16)(r >> 16);
}

union UB2 { u32x4 u; bf16x8 b; };
__device__ __forceinline__ bf16x8 as_bf(u32x4 u) { UB2 x; x.u = u; return x.b; }

__device__ __forceinline__ u32 relu2(u32 u) {
    u32 lo = (u & 0x8000u)     ? 0u : (u & 0xFFFFu);
    u32 hi = (u & 0x80000000u) ? 0u : (u & 0xFFFF0000u);
    return lo | hi;
}

// 16B LLC-bypass load (sc0 sc1): past L1 and L2, served at the coherence point.
__device__ __forceinline__ u32x4 ld16_llc(const void* p) {
    u32x4 r;
    asm volatile("global_load_dwordx4 %0, %1, off sc0 sc1"
                 : "=v"(r) : "v"(p) : "memory");
    return r;
}
// 16B L2-caching load (sc0 only): bypass L1, allocate in this XCD's L2.
// Safe ONLY for never-reused (virgin) addresses — deep-history mode.
__device__ __forceinline__ u32x4 ld16_l2(const void* p) {
    u32x4 r;
    asm volatile("global_load_dwordx4 %0, %1, off sc0"
                 : "=v"(r) : "v"(p) : "memory");
    return r;
}
__device__ __forceinline__ void wait_vm0() {
    asm volatile("s_waitcnt vmcnt(0)" ::: "memory");
    __builtin_amdgcn_sched_barrier(0);
}
__device__ __forceinline__ void vm0() {          // drain own stores to coherence point
    asm volatile("s_waitcnt vmcnt(0)" ::: "memory");
}

// ---------------- prep kernels ----------------

__global__ void k_zero(u32* dst, int n) {
    int i = blockIdx.x * blockDim.x + threadIdx.x;
    if (i < n) dst[i] = 0u;
}

__global__ void k_bias(const float* __restrict__ bih0, const float* __restrict__ bhh0,
                       const float* __restrict__ bih1, const float* __restrict__ bhh1,
                       float* __restrict__ bias0, float* __restrict__ bias1) {
    int i = blockIdx.x * blockDim.x + threadIdx.x;
    if (i < NG) {
        int orig = (i & 3) * HID + (i >> 2);
        bias0[i] = bih0[orig] + bhh0[orig];
        bias1[i] = bih1[orig] + bhh1[orig];
    }
}

__global__ void k_xconv(const float* __restrict__ x, u16* __restrict__ xbf) {
    int i = blockIdx.x * blockDim.x + threadIdx.x;   // exactly 2097152 threads
    float4 v = reinterpret_cast<const float4*>(x)[i];
    u32 lo = (u32)f2bf(v.x) | ((u32)f2bf(v.y) << 16);
    u32 hi = (u32)f2bf(v.z) | ((u32)f2bf(v.w) << 16);
    reinterpret_cast<uint2*>(xbf)[i] = make_uint2(lo, hi);
}

// LDS-ready layout per WG: [ks][kb(4)][n(32)][8], value = W[p = wg*32+n][k = 32ks+8kb+j]
__global__ void k_wconv(const float* __restrict__ wih0, const float* __restrict__ whh0,
                        const float* __restrict__ wih1, const float* __restrict__ whh1,
                        const float* __restrict__ fcw,
                        u16* __restrict__ wl0, u16* __restrict__ wl1, u16* __restrict__ wfc) {
    int i = blockIdx.x * blockDim.x + threadIdx.x;   // exactly 3473408 threads
    if (i < 64 * 20480) {                            // layer0: K=640 (512 hh + 128 ih)
        int wg = i / 20480, r = i % 20480;
        int ks = r / 1024, kb = (r % 1024) / 256, n = (r % 256) / 8, j = r % 8;
        int k = ks * 32 + kb * 8 + j;
        int p = wg * 32 + n;
        int orig = (p & 3) * HID + (p >> 2);
        float v = (k < HID) ? whh0[orig * HID + k] : wih0[orig * INDIM + (k - HID)];
        wl0[i] = f2bf(v);
        return;
    }
    int i1 = i - 64 * 20480;
    if (i1 < 64 * 32768) {                           // layer1: K=1024 (512 ih(h0) + 512 hh(h1))
        int wg = i1 / 32768, r = i1 % 32768;
        int ks = r / 1024, kb = (r % 1024) / 256, n = (r % 256) / 8, j = r % 8;
        int k = ks * 32 + kb * 8 + j;
        int p = wg * 32 + n;
        int orig = (p & 3) * HID + (p >> 2);
        float v = (k < HID) ? wih1[orig * HID + k] : whh1[orig * HID + (k - HID)];
        wl1[i1] = f2bf(v);
        return;
    }
    int i2 = i1 - 64 * 32768;
    if (i2 < 4 * 16384) {                            // fc: K=512, no row permutation
        int wg = i2 / 16384, r = i2 % 16384;
        int ks = r / 1024, kb = (r % 1024) / 256, n = (r % 256) / 8, j = r % 8;
        int k = ks * 32 + kb * 8 + j;
        int o = wg * 32 + n;
        wfc[i2] = f2bf(fcw[o * HID + k]);
    }
}

// ---------------- persistent fused LSTM ----------------
//
// R7 skeleton with two changes:
//  1. DEEP-mode sync via aggregated epoch counters: producers atomicAdd ONE
//     line cnt[role][t&7] (monotonic, expected 64*((t>>3)+1)); exactly one
//     thread per dependency polls one line.  Kills the 130-WG x 100-line
//     agent-scope poll storm that was inflating every RT in the serial chain.
//     (Deep history => no WAR edges => counters are the only sync.)
//  2. LDS h-stage row stride padded 128->130 u64 (rows advance 4 banks) —
//     removes R7's 4.1e8 scatter bank conflicts; fragment reads stay 2-way.
// Shallow fallback keeps the proven per-WG flag protocol verbatim.

__global__ __launch_bounds__(256, 1)
void k_lstm(const u16* __restrict__ xbf,
            const u16* __restrict__ wl0g, const u16* __restrict__ wl1g, const u16* __restrict__ wfcg,
            const float* __restrict__ bias0, const float* __restrict__ bias1, const float* __restrict__ fcb,
            u16* __restrict__ h0ring, u16* __restrict__ h1ring,
            u32* __restrict__ flags, float* __restrict__ dout, const int deep)
{
    __shared__ u16 wlds[32768];                      // 64 KB weights
    __shared__ __align__(16) u64 hq[2][32 * HQS];    // 2 x 32.5 KB h staging (padded)
    const int tid  = threadIdx.x;
    const int lane = tid & 63;
    const int wv   = tid >> 6;
    const int mt   = wv >> 1;                        // batch-half tile
    const int nt   = wv & 1;                         // col tile
    const int ci   = lane & 15;
    const int quad = lane >> 4;
    const int wg   = blockIdx.x;

    int role, rwg;
    if      (wg < L0_WGS)           { role = 0; rwg = wg; }
    else if (wg < L0_WGS + L1_WGS)  { role = 1; rwg = wg - L0_WGS; }
    else                            { role = 2; rwg = wg - L0_WGS - L1_WGS; }

    u32* flagL0 = flags;
    u32* flagL1 = flags + 64 * 16;
    u32* flagFC = flags + 128 * 16;
    u32* myflag = flags + wg * 16;
    u32* cnt0   = flags + F_CNT0;                    // [8] @ 64B stride
    u32* cnt1   = flags + F_CNT1;

    {   // stage this WG's weight slice into LDS (once)
        const u16* src = (role == 0) ? (wl0g + rwg * 20480)
                       : (role == 1) ? (wl1g + rwg * 32768)
                                     : (wfcg + rwg * 16384);
        const int n4 = (role == 0) ? 2560 : (role == 1) ? 4096 : 2048;
        uint4* d4 = reinterpret_cast<uint4*>(wlds);
        const uint4* s4 = reinterpret_cast<const uint4*>(src);
        for (int i = tid; i < n4; i += 256) d4[i] = s4[i];
    }
    __syncthreads();

    const bf16x8* wp = reinterpret_cast<const bf16x8*>(wlds);
    const int wbase  = quad * 32 + nt * 16 + ci;     // + ks*128
    const int pcol   = rwg * 32 + nt * 16 + ci;      // permuted gate col (roles 0/1) or out col (fc)
    const int gateid = pcol & 3;                     // 0=i 1=f 2=g 3=o
    const float bias = (role == 0) ? bias0[pcol] : (role == 1) ? bias1[pcol] : fcb[pcol];
    const int brow0  = mt * 16 + quad * 4;           // C/D: batch of acc reg r is brow0+r
    const int arow   = mt * 16 + ci;                 // A-frag batch row
    const int jidx   = pcol >> 2;                    // h index owned (roles 0/1)
    const int hswz   = arow & 7;                     // pair swizzle for fragment reads

    float cst[4] = {0.f, 0.f, 0.f, 0.f};             // c-state, f32, replicated x4 lanes

    auto spin = [&](u32* f, int target) {            // shallow per-WG flag spin
        if (target > 0)
            while ((int)__hip_atomic_load(f, __ATOMIC_RELAXED, __HIP_MEMORY_SCOPE_AGENT) < target)
                __builtin_amdgcn_s_sleep(1);
    };
    auto spinC = [&](u32* f, u32 target) {           // deep aggregated-counter spin
        while (__hip_atomic_load(f, __ATOMIC_RELAXED, __HIP_MEMORY_SCOPE_AGENT) < target)
            __builtin_amdgcn_s_sleep(1);
    };
    // expected counter value once all N producers finished step t (slots mod 8)
    auto expv = [&](int t, u32 n) -> u32 { return n * (u32)((t >> 3) + 1); };

    // slot base (u64 units): deep = full history (written idx = t+1, slot 0 = h[-1])
    auto slotQ = [&](u16* ring, int t_h) -> u64* {
        long idx = deep ? (long)(t_h + 1) : (long)(t_h & 3);
        return reinterpret_cast<u64*>(ring) + idx * SLOT_Q;
    };

    // decode-scatter one staged 16B chunk (u64s g0=2c, g0+1) into LDS
    auto scat = [&](int buf, int c, u32x4 b) {
        int g0  = 2 * c;
        int rw_ = g0 >> 6, nt_ = (g0 >> 5) & 1, mt_ = (g0 >> 4) & 1;
        int qd  = (g0 >> 2) & 3, c0 = g0 & 3;        // c0 in {0,2}
        int row = mt_ * 16 + qd * 4 + c0;
        int u   = rw_ * 2 + nt_;                     // 4-col granule 0..127
        int p   = u >> 1, ub = u & 1;
        hq[buf][ row      * HQS + (((p ^ ( row      & 7)) << 1) | ub)] = (u64)b[0] | ((u64)b[1] << 32);
        hq[buf][(row + 1) * HQS + (((p ^ ((row + 1) & 7)) << 1) | ub)] = (u64)b[2] | ((u64)b[3] << 32);
    };

    // cooperative stage of one 32KB slot (2048 x 16B), 8 chunks/thread
    auto stage1 = [&](const u64* sq, int buf) {
        u32x4 b[8];
        if (deep) {
            #pragma unroll
            for (int r = 0; r < 8; ++r) b[r] = ld16_l2(sq + 2 * (tid + r * 256));
        } else {
            #pragma unroll
            for (int r = 0; r < 8; ++r) b[r] = ld16_llc(sq + 2 * (tid + r * 256));
        }
        wait_vm0();
        #pragma unroll
        for (int r = 0; r < 8; ++r) scat(buf, tid + r * 256, b[r]);
    };
    auto stage2 = [&](const u64* s0, const u64* s1) {   // both slots, one drain
        u32x4 b0[8], b1[8];
        if (deep) {
            #pragma unroll
            for (int r = 0; r < 8; ++r) b0[r] = ld16_l2(s0 + 2 * (tid + r * 256));
            #pragma unroll
            for (int r = 0; r < 8; ++r) b1[r] = ld16_l2(s1 + 2 * (tid + r * 256));
        } else {
            #pragma unroll
            for (int r = 0; r < 8; ++r) b0[r] = ld16_llc(s0 + 2 * (tid + r * 256));
            #pragma unroll
            for (int r = 0; r < 8; ++r) b1[r] = ld16_llc(s1 + 2 * (tid + r * 256));
        }
        wait_vm0();
        #pragma unroll
        for (int r = 0; r < 8; ++r) scat(0, tid + r * 256, b0[r]);
        #pragma unroll
        for (int r = 0; r < 8; ++r) scat(1, tid + r * 256, b1[r]);
    };

    // epilogue: gates -> c,h; shfl-transpose; ONE 8B agent store per active
    // lane, 16 consecutive u64 per wave = 2 full 64B lines (write-combined)
    auto epi = [&](const f32x4& acc, u64* sq) {
        float ga[4], hv[4];
        #pragma unroll
        for (int r = 0; r < 4; ++r) {
            float g  = acc[r] + bias;
            float sv = 1.0f / (1.0f + __expf(-g));
            float tv = 1.0f - 2.0f / (__expf(2.0f * g) + 1.0f);
            ga[r] = (gateid == 2) ? tv : sv;
        }
        const int bl = lane & ~3;
        #pragma unroll
        for (int r = 0; r < 4; ++r) {
            float iv = __shfl(ga[r], bl + 0);
            float fv = __shfl(ga[r], bl + 1);
            float gv = __shfl(ga[r], bl + 2);
            float ov = __shfl(ga[r], bl + 3);
            float cn = fv * cst[r] + iv * gv;
            cst[r] = cn;
            hv[r] = ov * (1.0f - 2.0f / (__expf(2.0f * cn) + 1.0f));
        }
        u32 lo = 0, hi = 0;
        #pragma unroll
        for (int r = 0; r < 4; ++r) {                // gather row brow0+r into lane ci==r
            float c0 = __shfl(hv[r], (quad << 4) + 0);   // col jidx0+0
            float c1 = __shfl(hv[r], (quad << 4) + 4);   // +1
            float c2 = __shfl(hv[r], (quad << 4) + 8);   // +2
            float c3 = __shfl(hv[r], (quad << 4) + 12);  // +3
            if (ci == r) {
                lo = (u32)f2bf(c0) | ((u32)f2bf(c1) << 16);
                hi = (u32)f2bf(c2) | ((u32)f2bf(c3) << 16);
            }
        }
        if (ci < 4) {
            u64* dst = sq + rwg * 64 + nt * 32 + mt * 16 + quad * 4 + ci;
            u64 val = (u64)lo | ((u64)hi << 32);
            __hip_atomic_store(dst, val, __ATOMIC_RELAXED, __HIP_MEMORY_SCOPE_AGENT);
        }
    };

    // 16 MFMAs with A-fragments from LDS stage buffer (pair-swizzled, padded)
    #define HMFMA16S(BUF, KSOFF)                                                 \
        _Pragma("unroll")                                                        \
        for (int _k = 0; _k < 16; ++_k) {                                        \
          u32x4 _hv = *reinterpret_cast<const u32x4*>(                           \
              &hq[BUF][arow * HQS + (((_k * 4 + quad) ^ hswz) << 1)]);           \
          bf16x8 _bv = wp[wbase + (_k + (KSOFF)) * 128];                         \
          if (_k & 1) accB = __builtin_amdgcn_mfma_f32_16x16x32_bf16(as_bf(_hv), _bv, accB, 0, 0, 0); \
          else        accA = __builtin_amdgcn_mfma_f32_16x16x32_bf16(as_bf(_hv), _bv, accA, 0, 0, 0); \
        }

    auto fcTileS = [&](int buf) -> f32x4 {           // fc tile from staged h (with relu)
        f32x4 accA = {0.f,0.f,0.f,0.f}, accB = {0.f,0.f,0.f,0.f};
        #pragma unroll
        for (int ks = 0; ks < 16; ++ks) {
            u32x4 v = *reinterpret_cast<const u32x4*>(
                &hq[buf][arow * HQS + (((ks * 4 + quad) ^ hswz) << 1)]);
            v[0] = relu2(v[0]); v[1] = relu2(v[1]); v[2] = relu2(v[2]); v[3] = relu2(v[3]);
            bf16x8 bv = wp[wbase + ks * 128];
            if (ks & 1) accB = __builtin_amdgcn_mfma_f32_16x16x32_bf16(as_bf(v), bv, accB, 0, 0, 0);
            else        accA = __builtin_amdgcn_mfma_f32_16x16x32_bf16(as_bf(v), bv, accA, 0, 0, 0);
        }
        return accA + accB;
    };

    if (role == 0) {
        u32* pf = (!deep && tid < 64) ? (flagL0 + tid * 16)
                : (!deep && tid < 128) ? (flagL1 + (tid - 64) * 16) : nullptr;
        const int po = (tid < 64) ? 0 : -3;
        for (int t = 0; t < T_STEPS; ++t) {
            // x-part MFMAs don't depend on h: do them before the wait
            const u16* xA = xbf + (arow * T_STEPS + t) * INDIM + quad * 8;
            f32x4 accA = {0.f, 0.f, 0.f, 0.f}, accB = {0.f, 0.f, 0.f, 0.f};
            u32x4 xv[4];
            #pragma unroll
            for (int k4 = 0; k4 < 4; ++k4) xv[k4] = *reinterpret_cast<const u32x4*>(xA + k4 * 32);
            #pragma unroll
            for (int k4 = 0; k4 < 4; ++k4) {
                bf16x8 bv = wp[wbase + (16 + k4) * 128];
                if (k4 & 1) accB = __builtin_amdgcn_mfma_f32_16x16x32_bf16(as_bf(xv[k4]), bv, accB, 0, 0, 0);
                else        accA = __builtin_amdgcn_mfma_f32_16x16x32_bf16(as_bf(xv[k4]), bv, accA, 0, 0, 0);
            }
            if (deep) {
                if (tid == 0 && t > 0) spinC(cnt0 + ((t - 1) & 7) * 16, expv(t - 1, 64));
            } else if (pf) spin(pf, t + po);
            __syncthreads();
            stage1(slotQ(h0ring, t - 1), 0);          // h0[t-1], once per WG
            __syncthreads();
            HMFMA16S(0, 0);
            epi(accA + accB, slotQ(h0ring, t));
            vm0();                                    // h stores complete at coherence point
            __syncthreads();
            if (tid == 0) {
                if (deep) atomicAdd(cnt0 + (t & 7) * 16, 1u);
                else __hip_atomic_store(myflag, (u32)(t + 1), __ATOMIC_RELAXED, __HIP_MEMORY_SCOPE_AGENT);
            }
        }
    } else if (role == 1) {
        u32* pf = (!deep && tid < 64)  ? (flagL0 + tid * 16)
                : (!deep && tid < 128) ? (flagL1 + (tid - 64) * 16)
                : (!deep && tid < 132) ? (flagFC + (tid - 128) * 16) : nullptr;
        const int po = (tid < 64) ? 1 : (tid < 128) ? 0 : -3;
        for (int t = 0; t < T_STEPS; ++t) {
            if (deep) {
                if (tid == 0)               spinC(cnt0 + (t & 7) * 16, expv(t, 64));
                else if (tid == 64 && t > 0) spinC(cnt1 + ((t - 1) & 7) * 16, expv(t - 1, 64));
            } else if (pf) spin(pf, t + po);
            __syncthreads();
            stage2(slotQ(h0ring, t),                  // h0[t]   -> buf 0
                   slotQ(h1ring, t - 1));             // h1[t-1] -> buf 1
            __syncthreads();
            f32x4 accA = {0.f, 0.f, 0.f, 0.f}, accB = {0.f, 0.f, 0.f, 0.f};
            HMFMA16S(0, 0);                           // K 0..511: h0[t] (W_ih1)
            HMFMA16S(1, 16);                          // K 512..1023: h1[t-1] (W_hh1)
            epi(accA + accB, slotQ(h1ring, t));
            vm0();                                    // h stores complete at coherence point
            __syncthreads();
            if (tid == 0) {
                if (deep) atomicAdd(cnt1 + (t & 7) * 16, 1u);
                else __hip_atomic_store(myflag, (u32)(t + 1), __ATOMIC_RELAXED, __HIP_MEMORY_SCOPE_AGENT);
            }
        }
    } else {
        u32* pf = (!deep && tid < 64) ? (flagL1 + tid * 16) : nullptr;
        for (int t = 0; t < T_STEPS; ++t) {
            if (deep) {
                if (tid == 0) spinC(cnt1 + (t & 7) * 16, expv(t, 64));
            } else if (pf) spin(pf, t + 1);
            __syncthreads();
            stage1(slotQ(h1ring, t), 0);
            __syncthreads();
            f32x4 acc = fcTileS(0);
            #pragma unroll
            for (int r = 0; r < 4; ++r)
                dout[((brow0 + r) * T_STEPS + t) * OUTD + pcol] = acc[r] + bias;
            __syncthreads();                          // all reads of slot done before flag
            if (tid == 0 && !deep)
                __hip_atomic_store(myflag, (u32)(t + 1), __ATOMIC_RELAXED, __HIP_MEMORY_SCOPE_AGENT);
        }
        // hidden = fc(relu(h_n)); hq[0] still holds h1[2047] from the last iteration
        stage1(slotQ(h0ring, T_STEPS - 1), 1);
        __syncthreads();
        f32x4 hh1 = fcTileS(0);
        f32x4 hh0 = fcTileS(1);
        #pragma unroll
        for (int r = 0; r < 4; ++r)
            dout[HID_OFF + (brow0 + r) * OUTD + pcol] = hh0[r] + bias;
        #pragma unroll
        for (int r = 0; r < 4; ++r)
            dout[HID_OFF + (BATCH + brow0 + r) * OUTD + pcol] = hh1[r] + bias;
    }

    // c_n output [2, 32, 512]
    if (role <= 1 && (ci & 3) == 0) {
        #pragma unroll
        for (int r = 0; r < 4; ++r)
            dout[CN_OFF + (role * BATCH + brow0 + r) * HID + jidx] = cst[r];
    }
}

// ---------------- launch ----------------

extern "C" void kernel_launch(void* const* d_in, const int* in_sizes, int n_in,
                              void* d_out, int out_size, void* d_ws, size_t ws_size,
                              hipStream_t stream) {
    const float* x    = (const float*)d_in[0];
    const float* wih0 = (const float*)d_in[1];
    const float* whh0 = (const float*)d_in[2];
    const float* bih0 = (const float*)d_in[3];
    const float* bhh0 = (const float*)d_in[4];
    const float* wih1 = (const float*)d_in[5];
    const float* whh1 = (const float*)d_in[6];
    const float* bih1 = (const float*)d_in[7];
    const float* bhh1 = (const float*)d_in[8];
    const float* fcw  = (const float*)d_in[9];
    const float* fcb  = (const float*)d_in[10];

    char* ws = (char*)d_ws;
    u32*  flags = (u32*)(ws + WS_FLAGS);
    float* b0   = (float*)(ws + WS_BIAS0);
    float* b1   = (float*)(ws + WS_BIAS1);
    u16*  wfc   = (u16*)(ws + WS_WFC);
    u16*  wl0   = (u16*)(ws + WS_WL0);
    u16*  wl1   = (u16*)(ws + WS_WL1);
    u16*  xbf   = (u16*)(ws + WS_XBF);
    float* dout = (float*)d_out;

    const int deep = (ws_size >= (size_t)WS_DEEPEND) ? 1 : 0;
    u16* h0r = deep ? (u16*)(ws + WS_H0DEEP) : (u16*)(ws + WS_H0RING);
    u16* h1r = deep ? (u16*)(ws + WS_H1DEEP) : (u16*)(ws + WS_H1RING);

    if (deep) {
        // zero: flags+counters (16 KB) + slot 0 of each deep ring (h[-1] = 0)
        k_zero<<<16, 256, 0, stream>>>((u32*)ws, 4096);
        k_zero<<<32, 256, 0, stream>>>((u32*)(ws + WS_H0DEEP), 8192);
        k_zero<<<32, 256, 0, stream>>>((u32*)(ws + WS_H1DEEP), 8192);
    } else {
        // shallow fallback: flags + both 4-slot rings
        k_zero<<<272, 256, 0, stream>>>((u32*)ws, 69632);
    }
    k_bias<<<8, 256, 0, stream>>>(bih0, bhh0, bih1, bhh1, b0, b1);
    k_xconv<<<8192, 256, 0, stream>>>(x, xbf);
    k_wconv<<<13568, 256, 0, stream>>>(wih0, whh0, wih1, whh1, fcw, wl0, wl1, wfc);
    k_lstm<<<NWG, 256, 0, stream>>>(xbf, wl0, wl1, wfc, b0, b1, fcb,
                                    h0r, h1r, flags, dout, deep);
}

// Round 9
// 9041.473 us; speedup vs baseline: 1.7816x; 1.7816x over previous
//
#include <hip/hip_runtime.h>

typedef unsigned int u32;
typedef unsigned short u16;
typedef unsigned long long u64;

#define T_STEPS 2048
#define BATCH   32
#define HID     512
#define INDIM   128
#define OUTD    128
#define NG      2048
#define L0_WGS  64
#define L1_WGS  64
#define FC_WGS  4
#define NWG     (L0_WGS + L1_WGS + FC_WGS)
#define BH      (BATCH * HID)

#define HID_OFF 8388608           // 32*2048*128
#define CN_OFF  8396800           // + 2*32*128

// ws layout (bytes) — v5 layout with flag region widened to 32 KB for replicas
#define WS_FLAGS   0                         // replicated flags (32 KB reserved)
#define WS_H0RING  32768
#define WS_H1RING  (WS_H0RING + 131072)      // 4*32*512*2
#define WS_BIAS0   (WS_H1RING + 131072)
#define WS_BIAS1   (WS_BIAS0 + 8192)
#define WS_WFC     (WS_BIAS1 + 8192)         // 4 * 16384 u16
#define WS_WL0     (WS_WFC + 131072)         // 64 * 20480 u16
#define WS_WL1     (WS_WL0 + 2621440)        // 64 * 32768 u16
#define WS_XBF     (WS_WL1 + 4194304)        // 32*2048*128 u16

typedef __bf16 bf16x8 __attribute__((ext_vector_type(8)));
typedef float  f32x4  __attribute__((ext_vector_type(4)));
typedef unsigned int u32x4 __attribute__((ext_vector_type(4)));

__device__ __forceinline__ u16 f2bf(float f) {
    u32 u = __float_as_uint(f);
    u32 r = u + 0x7FFFu + ((u >> 16) & 1u);
    return (u16)(r >> 16);
}

union UB2 { u32x4 u; bf16x8 b; };
__device__ __forceinline__ bf16x8 as_bf(u32x4 u) { UB2 x; x.u = u; return x.b; }

__device__ __forceinline__ u32 relu2(u32 u) {
    u32 lo = (u & 0x8000u)     ? 0u : (u & 0xFFFFu);
    u32 hi = (u & 0x80000000u) ? 0u : (u & 0xFFFF0000u);
    return lo | hi;
}

// 16B LLC-bypass load (sc0 sc1: past L1 and L2, served at the coherence
// point). NON-atomic encoding; caller must wait_vm0() before use.
__device__ __forceinline__ u32x4 ld16_llc(const void* p) {
    u32x4 r;
    asm volatile("global_load_dwordx4 %0, %1, off sc0 sc1"
                 : "=v"(r) : "v"(p) : "memory");
    return r;
}
__device__ __forceinline__ void wait_vm0() {
    asm volatile("s_waitcnt vmcnt(0)" ::: "memory");
    __builtin_amdgcn_sched_barrier(0);
}
__device__ __forceinline__ void vm0() {          // drain own stores to coherence point
    asm volatile("s_waitcnt vmcnt(0)" ::: "memory");
}

// ---------------- prep kernels (unchanged) ----------------

__global__ void k_zero(u32* dst, int n) {
    int i = blockIdx.x * blockDim.x + threadIdx.x;
    if (i < n) dst[i] = 0u;
}

__global__ void k_bias(const float* __restrict__ bih0, const float* __restrict__ bhh0,
                       const float* __restrict__ bih1, const float* __restrict__ bhh1,
                       float* __restrict__ bias0, float* __restrict__ bias1) {
    int i = blockIdx.x * blockDim.x + threadIdx.x;
    if (i < NG) {
        int orig = (i & 3) * HID + (i >> 2);
        bias0[i] = bih0[orig] + bhh0[orig];
        bias1[i] = bih1[orig] + bhh1[orig];
    }
}

__global__ void k_xconv(const float* __restrict__ x, u16* __restrict__ xbf) {
    int i = blockIdx.x * blockDim.x + threadIdx.x;   // exactly 2097152 threads
    float4 v = reinterpret_cast<const float4*>(x)[i];
    u32 lo = (u32)f2bf(v.x) | ((u32)f2bf(v.y) << 16);
    u32 hi = (u32)f2bf(v.z) | ((u32)f2bf(v.w) << 16);
    reinterpret_cast<uint2*>(xbf)[i] = make_uint2(lo, hi);
}

// LDS-ready layout per WG: [ks][kb(4)][n(32)][8], value = W[p = wg*32+n][k = 32ks+8kb+j]
__global__ void k_wconv(const float* __restrict__ wih0, const float* __restrict__ whh0,
                        const float* __restrict__ wih1, const float* __restrict__ whh1,
                        const float* __restrict__ fcw,
                        u16* __restrict__ wl0, u16* __restrict__ wl1, u16* __restrict__ wfc) {
    int i = blockIdx.x * blockDim.x + threadIdx.x;   // exactly 3473408 threads
    if (i < 64 * 20480) {                            // layer0: K=640 (512 hh + 128 ih)
        int wg = i / 20480, r = i % 20480;
        int ks = r / 1024, kb = (r % 1024) / 256, n = (r % 256) / 8, j = r % 8;
        int k = ks * 32 + kb * 8 + j;
        int p = wg * 32 + n;
        int orig = (p & 3) * HID + (p >> 2);
        float v = (k < HID) ? whh0[orig * HID + k] : wih0[orig * INDIM + (k - HID)];
        wl0[i] = f2bf(v);
        return;
    }
    int i1 = i - 64 * 20480;
    if (i1 < 64 * 32768) {                           // layer1: K=1024 (512 ih(h0) + 512 hh(h1))
        int wg = i1 / 32768, r = i1 % 32768;
        int ks = r / 1024, kb = (r % 1024) / 256, n = (r % 256) / 8, j = r % 8;
        int k = ks * 32 + kb * 8 + j;
        int p = wg * 32 + n;
        int orig = (p & 3) * HID + (p >> 2);
        float v = (k < HID) ? wih1[orig * HID + k] : whh1[orig * HID + (k - HID)];
        wl1[i1] = f2bf(v);
        return;
    }
    int i2 = i1 - 64 * 32768;
    if (i2 < 4 * 16384) {                            // fc: K=512, no row permutation
        int wg = i2 / 16384, r = i2 % 16384;
        int ks = r / 1024, kb = (r % 1024) / 256, n = (r % 256) / 8, j = r % 8;
        int k = ks * 32 + kb * 8 + j;
        int o = wg * 32 + n;
        wfc[i2] = f2bf(fcw[o * HID + k]);
    }
}

// ---------------- persistent fused LSTM ----------------
//
// Exact v5 structure (proven 8.89 ms) + anti-congestion sync changes ONLY:
//  * per-producer flags REPLICATED per consumer class (fL0a/fL0b, fL1a/b/c)
//    so each flag line is polled by ~64 threads instead of ~130 — halves the
//    same-line request queue at the coherence point.
//  * poll cadence s_sleep(1)->s_sleep(4) (64->256 cy): cuts poll request rate
//    4x; adds <=0.1us detect quantization.
//  * producers fire all replicas after ONE vm0 drain (parallel stores).
// Data path (LDS staging, linear+swz layout, llc loads) byte-identical to v5.

__global__ __launch_bounds__(256, 1)
void k_lstm(const u16* __restrict__ xbf,
            const u16* __restrict__ wl0g, const u16* __restrict__ wl1g, const u16* __restrict__ wfcg,
            const float* __restrict__ bias0, const float* __restrict__ bias1, const float* __restrict__ fcb,
            u16* __restrict__ h0ring, u16* __restrict__ h1ring,
            u32* __restrict__ flags, float* __restrict__ dout)
{
    __shared__ u16   wlds[32768];                    // 64 KB weights
    __shared__ u32x4 hstage[2][2048];                // 2 x 32 KB h staging
    const int tid  = threadIdx.x;
    const int lane = tid & 63;
    const int wv   = tid >> 6;
    const int mt   = wv >> 1;                        // batch-half tile
    const int nt   = wv & 1;                         // col tile
    const int ci   = lane & 15;
    const int quad = lane >> 4;
    const int wg   = blockIdx.x;

    int role, rwg;
    if      (wg < L0_WGS)           { role = 0; rwg = wg; }
    else if (wg < L0_WGS + L1_WGS)  { role = 1; rwg = wg - L0_WGS; }
    else                            { role = 2; rwg = wg - L0_WGS - L1_WGS; }

    // replicated flag arrays (64B stride each); one replica per consumer class
    u32* fL0a = flags;                               // L0 progress — polled by L0 peers
    u32* fL0b = flags + 64 * 16;                     // L0 progress — polled by L1
    u32* fL1a = flags + 128 * 16;                    // L1 progress — polled by L0 (WAR)
    u32* fL1b = flags + 192 * 16;                    // L1 progress — polled by L1 peers
    u32* fL1c = flags + 256 * 16;                    // L1 progress — polled by FC
    u32* fFC  = flags + 320 * 16;                    // FC progress — polled by L1 (WAR)

    {   // stage this WG's weight slice into LDS (once)
        const u16* src = (role == 0) ? (wl0g + rwg * 20480)
                       : (role == 1) ? (wl1g + rwg * 32768)
                                     : (wfcg + rwg * 16384);
        const int n4 = (role == 0) ? 2560 : (role == 1) ? 4096 : 2048;
        uint4* d4 = reinterpret_cast<uint4*>(wlds);
        const uint4* s4 = reinterpret_cast<const uint4*>(src);
        for (int i = tid; i < n4; i += 256) d4[i] = s4[i];
    }
    __syncthreads();

    const bf16x8* wp = reinterpret_cast<const bf16x8*>(wlds);
    const int wbase  = quad * 32 + nt * 16 + ci;     // + ks*128
    const int pcol   = rwg * 32 + nt * 16 + ci;      // permuted gate col (roles 0/1) or out col (fc)
    const int gateid = pcol & 3;                     // 0=i 1=f 2=g 3=o
    const float bias = (role == 0) ? bias0[pcol] : (role == 1) ? bias1[pcol] : fcb[pcol];
    const int brow0  = mt * 16 + quad * 4;           // C/D: batch of acc reg r is brow0+r
    const int arow   = mt * 16 + ci;                 // A-frag batch row
    const int jidx   = pcol >> 2;                    // h index owned (roles 0/1)
    const int hfrag  = arow * 64 + quad;             // LDS chunk base for fragments
    const int hswz   = arow & 7;                     // row XOR swizzle

    float cst[4] = {0.f, 0.f, 0.f, 0.f};             // c-state, f32, replicated x4 lanes

    auto spin = [&](u32* f, int target) {
        if (target > 0)
            while ((int)__hip_atomic_load(f, __ATOMIC_RELAXED, __HIP_MEMORY_SCOPE_AGENT) < target)
                __builtin_amdgcn_s_sleep(4);
    };
    auto stf = [&](u32* f, u32 v) {
        __hip_atomic_store(f, v, __ATOMIC_RELAXED, __HIP_MEMORY_SCOPE_AGENT);
    };

    // cooperative LLC->LDS stage of one 32KB slot (2048 x 16B), 8 chunks/thread
    auto stage1 = [&](const u16* slot, int buf) {
        u32x4 b[8];
        #pragma unroll
        for (int r = 0; r < 8; ++r) b[r] = ld16_llc(slot + (tid + r * 256) * 8);
        wait_vm0();
        #pragma unroll
        for (int r = 0; r < 8; ++r) {
            int c = tid + r * 256;
            hstage[buf][c ^ ((c >> 6) & 7)] = b[r];
        }
    };
    auto stage2 = [&](const u16* s0, const u16* s1) {   // both slots, one drain
        u32x4 b0[8], b1[8];
        #pragma unroll
        for (int r = 0; r < 8; ++r) b0[r] = ld16_llc(s0 + (tid + r * 256) * 8);
        #pragma unroll
        for (int r = 0; r < 8; ++r) b1[r] = ld16_llc(s1 + (tid + r * 256) * 8);
        wait_vm0();
        #pragma unroll
        for (int r = 0; r < 8; ++r) {
            int c = tid + r * 256;
            int cs = c ^ ((c >> 6) & 7);
            hstage[0][cs] = b0[r];
            hstage[1][cs] = b1[r];
        }
    };

    // epilogue: gates -> c,h; shfl-transpose; one aligned 8B agent store per active lane
    auto epi = [&](const f32x4& acc, u16* slotb) {
        float ga[4], hv[4];
        #pragma unroll
        for (int r = 0; r < 4; ++r) {
            float g  = acc[r] + bias;
            float sv = 1.0f / (1.0f + __expf(-g));
            float tv = 1.0f - 2.0f / (__expf(2.0f * g) + 1.0f);
            ga[r] = (gateid == 2) ? tv : sv;
        }
        const int bl = lane & ~3;
        #pragma unroll
        for (int r = 0; r < 4; ++r) {
            float iv = __shfl(ga[r], bl + 0);
            float fv = __shfl(ga[r], bl + 1);
            float gv = __shfl(ga[r], bl + 2);
            float ov = __shfl(ga[r], bl + 3);
            float cn = fv * cst[r] + iv * gv;
            cst[r] = cn;
            hv[r] = ov * (1.0f - 2.0f / (__expf(2.0f * cn) + 1.0f));
        }
        u32 lo = 0, hi = 0;
        #pragma unroll
        for (int r = 0; r < 4; ++r) {                // gather row brow0+r into lane ci==r
            float c0 = __shfl(hv[r], (quad << 4) + 0);   // jidx = rwg*8+nt*4+0
            float c1 = __shfl(hv[r], (quad << 4) + 4);   // +1
            float c2 = __shfl(hv[r], (quad << 4) + 8);   // +2
            float c3 = __shfl(hv[r], (quad << 4) + 12);  // +3
            if (ci == r) {
                lo = (u32)f2bf(c0) | ((u32)f2bf(c1) << 16);
                hi = (u32)f2bf(c2) | ((u32)f2bf(c3) << 16);
            }
        }
        if (ci < 4) {
            u64* dst = reinterpret_cast<u64*>(slotb) + (brow0 + ci) * 128 + rwg * 2 + nt;
            u64 val = (u64)lo | ((u64)hi << 32);
            __hip_atomic_store(dst, val, __ATOMIC_RELAXED, __HIP_MEMORY_SCOPE_AGENT);
        }
    };

    // 16 MFMAs with A-fragments from LDS stage buffer
    #define HMFMA16S(BUF, KSOFF)                                                 \
        _Pragma("unroll")                                                        \
        for (int _k = 0; _k < 16; ++_k) {                                        \
          u32x4 _hv = hstage[BUF][(hfrag + _k * 4) ^ hswz];                      \
          bf16x8 _bv = wp[wbase + (_k + (KSOFF)) * 128];                         \
          if (_k & 1) accB = __builtin_amdgcn_mfma_f32_16x16x32_bf16(as_bf(_hv), _bv, accB, 0, 0, 0); \
          else        accA = __builtin_amdgcn_mfma_f32_16x16x32_bf16(as_bf(_hv), _bv, accA, 0, 0, 0); \
        }

    auto fcTileS = [&](int buf) -> f32x4 {           // fc tile from staged h (with relu)
        f32x4 accA = {0.f,0.f,0.f,0.f}, accB = {0.f,0.f,0.f,0.f};
        #pragma unroll
        for (int ks = 0; ks < 16; ++ks) {
            u32x4 v = hstage[buf][(hfrag + ks * 4) ^ hswz];
            v[0] = relu2(v[0]); v[1] = relu2(v[1]); v[2] = relu2(v[2]); v[3] = relu2(v[3]);
            bf16x8 bv = wp[wbase + ks * 128];
            if (ks & 1) accB = __builtin_amdgcn_mfma_f32_16x16x32_bf16(as_bf(v), bv, accB, 0, 0, 0);
            else        accA = __builtin_amdgcn_mfma_f32_16x16x32_bf16(as_bf(v), bv, accA, 0, 0, 0);
        }
        return accA + accB;
    };

    if (role == 0) {
        u32* pf = (tid < 64) ? (fL0a + tid * 16) : (tid < 128) ? (fL1a + (tid - 64) * 16) : nullptr;
        const int po = (tid < 64) ? 0 : -3;
        for (int t = 0; t < T_STEPS; ++t) {
            // x-part MFMAs don't depend on h: do them before the wait (normal cached loads)
            const u16* xA = xbf + (arow * T_STEPS + t) * INDIM + quad * 8;
            f32x4 accA = {0.f, 0.f, 0.f, 0.f}, accB = {0.f, 0.f, 0.f, 0.f};
            u32x4 xv[4];
            #pragma unroll
            for (int k4 = 0; k4 < 4; ++k4) xv[k4] = *reinterpret_cast<const u32x4*>(xA + k4 * 32);
            #pragma unroll
            for (int k4 = 0; k4 < 4; ++k4) {
                bf16x8 bv = wp[wbase + (16 + k4) * 128];
                if (k4 & 1) accB = __builtin_amdgcn_mfma_f32_16x16x32_bf16(as_bf(xv[k4]), bv, accB, 0, 0, 0);
                else        accA = __builtin_amdgcn_mfma_f32_16x16x32_bf16(as_bf(xv[k4]), bv, accA, 0, 0, 0);
            }
            if (pf) spin(pf, t + po);
            __syncthreads();
            stage1(h0ring + ((t + 3) & 3) * BH, 0);   // h0[t-1], once per WG
            __syncthreads();
            HMFMA16S(0, 0);
            epi(accA + accB, h0ring + (t & 3) * BH);
            vm0();                                    // h stores complete at LLC
            __syncthreads();
            if (tid == 0) {
                stf(fL0a + rwg * 16, (u32)(t + 1));   // replicas: parallel stores, one drain
                stf(fL0b + rwg * 16, (u32)(t + 1));
            }
        }
    } else if (role == 1) {
        u32* pf = (tid < 64)  ? (fL0b + tid * 16)
                : (tid < 128) ? (fL1b + (tid - 64) * 16)
                : (tid < 132) ? (fFC + (tid - 128) * 16) : nullptr;
        const int po = (tid < 64) ? 1 : (tid < 128) ? 0 : -3;
        for (int t = 0; t < T_STEPS; ++t) {
            if (pf) spin(pf, t + po);
            __syncthreads();
            stage2(h0ring + (t & 3) * BH,             // h0[t]   -> buf 0
                   h1ring + ((t + 3) & 3) * BH);      // h1[t-1] -> buf 1
            __syncthreads();
            f32x4 accA = {0.f, 0.f, 0.f, 0.f}, accB = {0.f, 0.f, 0.f, 0.f};
            HMFMA16S(0, 0);                           // K 0..511: h0[t] (W_ih1)
            HMFMA16S(1, 16);                          // K 512..1023: h1[t-1] (W_hh1)
            epi(accA + accB, h1ring + (t & 3) * BH);
            vm0();                                    // h stores complete at LLC
            __syncthreads();
            if (tid == 0) {
                stf(fL1a + rwg * 16, (u32)(t + 1));
                stf(fL1b + rwg * 16, (u32)(t + 1));
                stf(fL1c + rwg * 16, (u32)(t + 1));
            }
        }
    } else {
        u32* pf = (tid < 64) ? (fL1c + tid * 16) : nullptr;
        for (int t = 0; t < T_STEPS; ++t) {
            if (pf) spin(pf, t + 1);
            __syncthreads();
            stage1(h1ring + (t & 3) * BH, 0);
            __syncthreads();
            f32x4 acc = fcTileS(0);
            #pragma unroll
            for (int r = 0; r < 4; ++r)
                dout[((brow0 + r) * T_STEPS + t) * OUTD + pcol] = acc[r] + bias;
            __syncthreads();                          // all reads of slot done before flag
            if (tid == 0)
                stf(fFC + rwg * 16, (u32)(t + 1));
        }
        // hidden = fc(relu(h_n)); h[T-1] lives in slot 3 of each ring (2047 & 3 == 3).
        // hstage[0] still holds h1[2047] from the last loop iteration.
        stage1(h0ring + 3 * BH, 1);
        __syncthreads();
        f32x4 hh1 = fcTileS(0);
        f32x4 hh0 = fcTileS(1);
        #pragma unroll
        for (int r = 0; r < 4; ++r)
            dout[HID_OFF + (brow0 + r) * OUTD + pcol] = hh0[r] + bias;
        #pragma unroll
        for (int r = 0; r < 4; ++r)
            dout[HID_OFF + (BATCH + brow0 + r) * OUTD + pcol] = hh1[r] + bias;
    }

    // c_n output [2, 32, 512]
    if (role <= 1 && (ci & 3) == 0) {
        #pragma unroll
        for (int r = 0; r < 4; ++r)
            dout[CN_OFF + (role * BATCH + brow0 + r) * HID + jidx] = cst[r];
    }
}

// ---------------- launch ----------------

extern "C" void kernel_launch(void* const* d_in, const int* in_sizes, int n_in,
                              void* d_out, int out_size, void* d_ws, size_t ws_size,
                              hipStream_t stream) {
    const float* x    = (const float*)d_in[0];
    const float* wih0 = (const float*)d_in[1];
    const float* whh0 = (const float*)d_in[2];
    const float* bih0 = (const float*)d_in[3];
    const float* bhh0 = (const float*)d_in[4];
    const float* wih1 = (const float*)d_in[5];
    const float* whh1 = (const float*)d_in[6];
    const float* bih1 = (const float*)d_in[7];
    const float* bhh1 = (const float*)d_in[8];
    const float* fcw  = (const float*)d_in[9];
    const float* fcb  = (const float*)d_in[10];

    char* ws = (char*)d_ws;
    u32*  flags = (u32*)(ws + WS_FLAGS);
    u16*  h0r   = (u16*)(ws + WS_H0RING);
    u16*  h1r   = (u16*)(ws + WS_H1RING);
    float* b0   = (float*)(ws + WS_BIAS0);
    float* b1   = (float*)(ws + WS_BIAS1);
    u16*  wfc   = (u16*)(ws + WS_WFC);
    u16*  wl0   = (u16*)(ws + WS_WL0);
    u16*  wl1   = (u16*)(ws + WS_WL1);
    u16*  xbf   = (u16*)(ws + WS_XBF);
    float* dout = (float*)d_out;

    // zero flags (32 KB) + h rings (256 KB) = 73728 u32
    k_zero<<<288, 256, 0, stream>>>((u32*)ws, 73728);
    k_bias<<<8, 256, 0, stream>>>(bih0, bhh0, bih1, bhh1, b0, b1);
    k_xconv<<<8192, 256, 0, stream>>>(x, xbf);
    k_wconv<<<13568, 256, 0, stream>>>(wih0, whh0, wih1, whh1, fcw, wl0, wl1, wfc);
    k_lstm<<<NWG, 256, 0, stream>>>(xbf, wl0, wl1, wfc, b0, b1, fcb,
                                    h0r, h1r, flags, dout);
}